// Round 2
// baseline (75.663 us; speedup 1.0000x reference)
//
#include <hip/hip_runtime.h>

namespace {

constexpr int B = 8, C = 4, H = 512, W = 1024, K = 5;
constexpr int HW = H * W;   // pixels per (b, c) plane
constexpr int NG = HW / 4;  // float4 groups per plane (131072)
constexpr int GX = 256;     // blocks per batch in x (2 grid-stride iters/thread)
constexpr float DV = 0.5f;  // DELTA_V
constexpr float DD = 3.0f;  // DELTA_D

// ws float layout (all slots written before read -> no zero-init needed):
//   partial1 [B][GX][25] : per-block {4 channel sums + count} x K
//   stats    [B][K][5]   : {mean_c0..mean_c3, count}
//   partial2 [B][GX][K]  : per-block masked var sums
constexpr int P1_OFF = 0;
constexpr int ST_OFF = B * GX * 25;         // 51200
constexpr int P2_OFF = ST_OFF + B * K * 5;  // 51400

__device__ __forceinline__ float wave_reduce(float v) {
#pragma unroll
  for (int m = 32; m; m >>= 1) v += __shfl_xor(v, m, 64);
  return v;
}

// Pass 1: per-(b,block) partial pixel counts and channel sums. No atomics.
__global__ __launch_bounds__(256) void pass1_kernel(
    const float* __restrict__ emb, const int* __restrict__ lab,
    float* __restrict__ p1) {
  const int b = blockIdx.y;
  const float4* __restrict__ ep =
      reinterpret_cast<const float4*>(emb + (size_t)b * C * HW);
  const int4* __restrict__ lp =
      reinterpret_cast<const int4*>(lab + (size_t)b * HW);

  float acc[25];  // [k][{c0,c1,c2,c3,cnt}] flat, compile-time indexed only
#pragma unroll
  for (int i = 0; i < 25; i++) acc[i] = 0.f;

  for (int g = blockIdx.x * blockDim.x + threadIdx.x; g < NG;
       g += GX * blockDim.x) {
    const int4 l4 = lp[g];
    const float4 e0 = ep[0 * NG + g];
    const float4 e1 = ep[1 * NG + g];
    const float4 e2 = ep[2 * NG + g];
    const float4 e3 = ep[3 * NG + g];
    const int ls[4] = {l4.x, l4.y, l4.z, l4.w};
    const float c0[4] = {e0.x, e0.y, e0.z, e0.w};
    const float c1[4] = {e1.x, e1.y, e1.z, e1.w};
    const float c2[4] = {e2.x, e2.y, e2.z, e2.w};
    const float c3[4] = {e3.x, e3.y, e3.z, e3.w};
#pragma unroll
    for (int j = 0; j < 4; j++) {
      const int l = ls[j];
#pragma unroll
      for (int k = 0; k < K; k++) {  // branchless predicated accumulate
        const float m = (l == k + 1) ? 1.f : 0.f;
        acc[k * 5 + 0] += m * c0[j];
        acc[k * 5 + 1] += m * c1[j];
        acc[k * 5 + 2] += m * c2[j];
        acc[k * 5 + 3] += m * c3[j];
        acc[k * 5 + 4] += m;
      }
    }
  }

  __shared__ float red[4][25];
  const int wave = threadIdx.x >> 6, lane = threadIdx.x & 63;
#pragma unroll
  for (int i = 0; i < 25; i++) {
    const float v = wave_reduce(acc[i]);
    if (lane == 0) red[wave][i] = v;
  }
  __syncthreads();
  if (threadIdx.x < 25) {
    p1[(size_t)(b * GX + blockIdx.x) * 25 + threadIdx.x] =
        red[0][threadIdx.x] + red[1][threadIdx.x] + red[2][threadIdx.x] +
        red[3][threadIdx.x];
  }
}

// Reduce pass-1 partials -> per-(b,k) means + counts. One block per b.
__global__ __launch_bounds__(256) void reduce1_kernel(
    const float* __restrict__ p1, float* __restrict__ stats) {
  const int b = blockIdx.x, t = threadIdx.x;
  float local[25];
  const float* base = p1 + (size_t)(b * GX + t) * 25;  // blockDim.x == GX
#pragma unroll
  for (int i = 0; i < 25; i++) local[i] = base[i];

  __shared__ float red[4][25];
  __shared__ float tot[25];
  const int wave = t >> 6, lane = t & 63;
#pragma unroll
  for (int i = 0; i < 25; i++) {
    const float v = wave_reduce(local[i]);
    if (lane == 0) red[wave][i] = v;
  }
  __syncthreads();
  if (t < 25) tot[t] = red[0][t] + red[1][t] + red[2][t] + red[3][t];
  __syncthreads();
  if (t < 25) {
    const float cnt = tot[(t / 5) * 5 + 4];
    stats[b * 25 + t] = (t % 5 == 4) ? cnt : tot[t] / cnt;
  }
}

// Pass 2: per-pixel relu(||e - mean_lane|| - DV)^2, per-(b,block,k) partials.
__global__ __launch_bounds__(256) void pass2_kernel(
    const float* __restrict__ emb, const int* __restrict__ lab,
    const float* __restrict__ stats, float* __restrict__ p2) {
  const int b = blockIdx.y;
  __shared__ float sm[K][C];
  if (threadIdx.x < K * C) {
    const int k = threadIdx.x / C, c = threadIdx.x % C;
    sm[k][c] = stats[b * 25 + k * 5 + c];  // already means
  }
  __syncthreads();

  const float4* __restrict__ ep =
      reinterpret_cast<const float4*>(emb + (size_t)b * C * HW);
  const int4* __restrict__ lp =
      reinterpret_cast<const int4*>(lab + (size_t)b * HW);

  float vacc[K] = {0.f, 0.f, 0.f, 0.f, 0.f};

  for (int g = blockIdx.x * blockDim.x + threadIdx.x; g < NG;
       g += GX * blockDim.x) {
    const int4 l4 = lp[g];
    const float4 e0 = ep[0 * NG + g];
    const float4 e1 = ep[1 * NG + g];
    const float4 e2 = ep[2 * NG + g];
    const float4 e3 = ep[3 * NG + g];
    const int ls[4] = {l4.x, l4.y, l4.z, l4.w};
    const float c0[4] = {e0.x, e0.y, e0.z, e0.w};
    const float c1[4] = {e1.x, e1.y, e1.z, e1.w};
    const float c2[4] = {e2.x, e2.y, e2.z, e2.w};
    const float c3[4] = {e3.x, e3.y, e3.z, e3.w};
#pragma unroll
    for (int j = 0; j < 4; j++) {
      const int l = ls[j];
      const int kk = (l > 0) ? (l - 1) : 0;  // safe index; l==0 masked out
      const float d0 = c0[j] - sm[kk][0];
      const float d1 = c1[j] - sm[kk][1];
      const float d2 = c2[j] - sm[kk][2];
      const float d3 = c3[j] - sm[kk][3];
      const float t =
          fmaxf(sqrtf(d0 * d0 + d1 * d1 + d2 * d2 + d3 * d3) - DV, 0.f);
      const float t2 = t * t;
#pragma unroll
      for (int k = 0; k < K; k++) vacc[k] += (l == k + 1) ? t2 : 0.f;
    }
  }

  __shared__ float red[4][K];
  const int wave = threadIdx.x >> 6, lane = threadIdx.x & 63;
#pragma unroll
  for (int i = 0; i < K; i++) {
    const float v = wave_reduce(vacc[i]);
    if (lane == 0) red[wave][i] = v;
  }
  __syncthreads();
  if (threadIdx.x < K) {
    p2[(size_t)(b * GX + blockIdx.x) * K + threadIdx.x] =
        red[0][threadIdx.x] + red[1][threadIdx.x] + red[2][threadIdx.x] +
        red[3][threadIdx.x];
  }
}

// Finalize: reduce var partials, pairwise-centroid term, faithful scan.
__global__ __launch_bounds__(256) void finalize_kernel(
    const float* __restrict__ stats, const float* __restrict__ p2,
    float* __restrict__ out) {
  const int t = threadIdx.x;  // t in [0, GX)
  const int wave = t >> 6, lane = t & 63;
  __shared__ float red[B * K][4];
#pragma unroll
  for (int i = 0; i < B * K; i++) {
    const int b = i / K, k = i % K;
    const float v = wave_reduce(p2[(size_t)(b * GX + t) * K + k]);
    if (lane == 0) red[i][wave] = v;
  }
  __syncthreads();
  if (t != 0) return;

  float v = 0.f, d = 0.f;
  for (int b = 0; b < B; b++) {
    float m[K][C], cnt[K];
#pragma unroll
    for (int k = 0; k < K; k++) {
      cnt[k] = stats[b * 25 + k * 5 + 4];
#pragma unroll
      for (int c = 0; c < C; c++) m[k][c] = stats[b * 25 + k * 5 + c];
    }
    float s = 0.f;
#pragma unroll
    for (int k = 0; k < K; k++) {
      const int i = b * K + k;
      s += (red[i][0] + red[i][1] + red[i][2] + red[i][3]) / cnt[k];
    }
    float p = 0.f;
#pragma unroll
    for (int i = 0; i < K; i++) {
#pragma unroll
      for (int j = 0; j < K; j++) {
        if (i == j) continue;  // diagonal term is exactly 0
        float dd = 0.f;
#pragma unroll
        for (int c = 0; c < C; c++) {
          const float tt = m[i][c] - m[j][c];
          dd += tt * tt;
        }
        const float r = fmaxf(DD - sqrtf(dd), 0.f);
        p += r * r;
      }
    }
    v = (v + s) / (float)K;
    d = (d + p) / (float)(2 * K * (K - 1));
  }
  out[0] = v / (float)B;
  out[1] = d / (float)B;
}

}  // namespace

extern "C" void kernel_launch(void* const* d_in, const int* in_sizes, int n_in,
                              void* d_out, int out_size, void* d_ws,
                              size_t ws_size, hipStream_t stream) {
  const float* emb = (const float*)d_in[0];
  const int* lab = (const int*)d_in[1];
  float* out = (float*)d_out;
  float* ws = (float*)d_ws;
  float* p1 = ws + P1_OFF;
  float* stats = ws + ST_OFF;
  float* p2 = ws + P2_OFF;

  dim3 grid(GX, B);
  pass1_kernel<<<grid, 256, 0, stream>>>(emb, lab, p1);
  reduce1_kernel<<<B, 256, 0, stream>>>(p1, stats);
  pass2_kernel<<<grid, 256, 0, stream>>>(emb, lab, stats, p2);
  finalize_kernel<<<1, 256, 0, stream>>>(stats, p2, out);
}

// Round 5
// 62.911 us; speedup vs baseline: 1.2027x; 1.2027x over previous
//
#include <hip/hip_runtime.h>

namespace {

constexpr int B = 8, C = 4, K = 5;
constexpr int HW = 512 * 1024;   // pixels per (b,c) plane
constexpr int NG = HW / 4;       // float4 groups per plane (131072)
constexpr int GX = 256;          // blocks per batch
constexpr int NT = 256;          // threads per block
constexpr int STRIDE = GX * NT;  // 65536 = NG/2 -> exactly 2 groups/thread
constexpr float DV = 0.5f;       // DELTA_V
constexpr float DD = 3.0f;       // DELTA_D

// ws float layout (every slot written before read on EVERY call, kernel
// boundaries are the only cross-block sync -> deterministic):
//   p1t   [B*25][GX] : per-block {4 channel sums + count} x K (transposed)
//   p2t   [B*K][GX]  : per-block masked var partials (transposed)
//   stats [B][25]    : {mean_c0..3, count} per (b,k) (written by gx==0)
constexpr int P1_OFF = 0;
constexpr int P2_OFF = P1_OFF + B * 25 * GX;  // 51200
constexpr int ST_OFF = P2_OFF + B * K * GX;   // 61440

__device__ __forceinline__ float wave_reduce(float v) {
#pragma unroll
  for (int m = 32; m; m >>= 1) v += __shfl_xor(v, m, 64);
  return v;
}

// Pass 1: straight-line 2-group accumulate -> transposed per-block partials.
__global__ __launch_bounds__(NT) void pass1_kernel(
    const float* __restrict__ emb, const int* __restrict__ lab,
    float* __restrict__ ws) {
  const int b = blockIdx.y, bx = blockIdx.x, tid = threadIdx.x;
  const int wv = tid >> 6, ln = tid & 63;
  const float4* __restrict__ ep =
      reinterpret_cast<const float4*>(emb + (size_t)b * C * HW);
  const int4* __restrict__ lp =
      reinterpret_cast<const int4*>(lab + (size_t)b * HW);
  const int g0 = bx * NT + tid, g1 = g0 + STRIDE;

  // All 10 loads issued up front (max MLP).
  const int4 la = lp[g0], lb2 = lp[g1];
  const float4 a0 = ep[g0], a1 = ep[NG + g0], a2 = ep[2 * NG + g0],
               a3 = ep[3 * NG + g0];
  const float4 b0 = ep[g1], b1 = ep[NG + g1], b2 = ep[2 * NG + g1],
               b3 = ep[3 * NG + g1];

  float acc[25];  // [k][{c0..c3,cnt}] flat, compile-time indexed only
#pragma unroll
  for (int i = 0; i < 25; i++) acc[i] = 0.f;

  auto accum = [&](int l, float v0, float v1, float v2, float v3) {
#pragma unroll
    for (int k = 0; k < K; k++) {  // branchless predicated accumulate
      const float m = (l == k + 1) ? 1.f : 0.f;
      acc[k * 5 + 0] = fmaf(m, v0, acc[k * 5 + 0]);
      acc[k * 5 + 1] = fmaf(m, v1, acc[k * 5 + 1]);
      acc[k * 5 + 2] = fmaf(m, v2, acc[k * 5 + 2]);
      acc[k * 5 + 3] = fmaf(m, v3, acc[k * 5 + 3]);
      acc[k * 5 + 4] += m;
    }
  };
  accum(la.x, a0.x, a1.x, a2.x, a3.x);
  accum(la.y, a0.y, a1.y, a2.y, a3.y);
  accum(la.z, a0.z, a1.z, a2.z, a3.z);
  accum(la.w, a0.w, a1.w, a2.w, a3.w);
  accum(lb2.x, b0.x, b1.x, b2.x, b3.x);
  accum(lb2.y, b0.y, b1.y, b2.y, b3.y);
  accum(lb2.z, b0.z, b1.z, b2.z, b3.z);
  accum(lb2.w, b0.w, b1.w, b2.w, b3.w);

  __shared__ float red[4][25];
#pragma unroll
  for (int i = 0; i < 25; i++) {
    const float v = wave_reduce(acc[i]);
    if (ln == 0) red[wv][i] = v;
  }
  __syncthreads();
  if (tid < 25) {
    ws[P1_OFF + (size_t)(b * 25 + tid) * GX + bx] =
        red[0][tid] + red[1][tid] + red[2][tid] + red[3][tid];
  }
}

// Pass 2: fold the stats reduction (each block redundantly reduces its
// batch's 25 partial rows from L2), then masked relu(||e-mean||-DV)^2 sums.
__global__ __launch_bounds__(NT) void pass2_kernel(
    const float* __restrict__ emb, const int* __restrict__ lab,
    float* __restrict__ ws) {
  const int b = blockIdx.y, bx = blockIdx.x, tid = threadIdx.x;
  const int wv = tid >> 6, ln = tid & 63;

  // --- stats fold: reduce p1t rows for this batch (25 rows x 256 floats) ---
  __shared__ float tot[25];
  for (int r = wv; r < 25; r += 4) {
    const float4 v = reinterpret_cast<const float4*>(
        ws + P1_OFF + (size_t)(b * 25 + r) * GX)[ln];
    float s = (v.x + v.y) + (v.z + v.w);
    s = wave_reduce(s);
    if (ln == 0) tot[r] = s;
  }
  __syncthreads();
  __shared__ float sm[K][C];
  if (tid < K * C) {
    const int k = tid / C, c = tid % C;
    sm[k][c] = tot[k * 5 + c] / tot[k * 5 + 4];
  }
  if (bx == 0 && tid < 25) {  // publish stats for finalize
    const float cnt = tot[(tid / 5) * 5 + 4];
    ws[ST_OFF + b * 25 + tid] = (tid % 5 == 4) ? cnt : tot[tid] / cnt;
  }
  __syncthreads();

  const float4* __restrict__ ep =
      reinterpret_cast<const float4*>(emb + (size_t)b * C * HW);
  const int4* __restrict__ lp =
      reinterpret_cast<const int4*>(lab + (size_t)b * HW);
  const int g0 = bx * NT + tid, g1 = g0 + STRIDE;

  const int4 la = lp[g0], lb2 = lp[g1];
  const float4 a0 = ep[g0], a1 = ep[NG + g0], a2 = ep[2 * NG + g0],
               a3 = ep[3 * NG + g0];
  const float4 b0 = ep[g1], b1 = ep[NG + g1], b2 = ep[2 * NG + g1],
               b3 = ep[3 * NG + g1];

  float vacc[K] = {0.f, 0.f, 0.f, 0.f, 0.f};
  auto accum = [&](int l, float v0, float v1, float v2, float v3) {
    const int kk = (l > 0) ? (l - 1) : 0;  // safe index; l==0 masked below
    const float d0 = v0 - sm[kk][0];
    const float d1 = v1 - sm[kk][1];
    const float d2 = v2 - sm[kk][2];
    const float d3 = v3 - sm[kk][3];
    const float t =
        fmaxf(sqrtf(d0 * d0 + d1 * d1 + d2 * d2 + d3 * d3) - DV, 0.f);
    const float t2 = t * t;
#pragma unroll
    for (int k = 0; k < K; k++) vacc[k] += (l == k + 1) ? t2 : 0.f;
  };
  accum(la.x, a0.x, a1.x, a2.x, a3.x);
  accum(la.y, a0.y, a1.y, a2.y, a3.y);
  accum(la.z, a0.z, a1.z, a2.z, a3.z);
  accum(la.w, a0.w, a1.w, a2.w, a3.w);
  accum(lb2.x, b0.x, b1.x, b2.x, b3.x);
  accum(lb2.y, b0.y, b1.y, b2.y, b3.y);
  accum(lb2.z, b0.z, b1.z, b2.z, b3.z);
  accum(lb2.w, b0.w, b1.w, b2.w, b3.w);

  __shared__ float red2[4][K];
#pragma unroll
  for (int i = 0; i < K; i++) {
    const float v = wave_reduce(vacc[i]);
    if (ln == 0) red2[wv][i] = v;
  }
  __syncthreads();
  if (tid < K) {
    ws[P2_OFF + (size_t)(b * K + tid) * GX + bx] =
        red2[0][tid] + red2[1][tid] + red2[2][tid] + red2[3][tid];
  }
}

// Finalize: reduce var partials + pairwise-centroid term + faithful scan.
__global__ __launch_bounds__(NT) void finalize_kernel(
    const float* __restrict__ ws, float* __restrict__ out) {
  const int tid = threadIdx.x, wv = tid >> 6, ln = tid & 63;
  __shared__ float tot2[B * K];
#pragma unroll
  for (int j = 0; j < 10; j++) {
    const int r = wv * 10 + j;
    const float4 v =
        reinterpret_cast<const float4*>(ws + P2_OFF + (size_t)r * GX)[ln];
    float s = (v.x + v.y) + (v.z + v.w);
    s = wave_reduce(s);
    if (ln == 0) tot2[r] = s;
  }
  __syncthreads();
  if (tid != 0) return;

  float v = 0.f, d = 0.f;
  for (int bb = 0; bb < B; bb++) {
    float m[K][C], cnt[K];
#pragma unroll
    for (int k = 0; k < K; k++) {
      cnt[k] = ws[ST_OFF + bb * 25 + k * 5 + 4];
#pragma unroll
      for (int c = 0; c < C; c++) m[k][c] = ws[ST_OFF + bb * 25 + k * 5 + c];
    }
    float s = 0.f;
#pragma unroll
    for (int k = 0; k < K; k++) s += tot2[bb * K + k] / cnt[k];
    float p = 0.f;
#pragma unroll
    for (int i = 0; i < K; i++) {
#pragma unroll
      for (int j = 0; j < K; j++) {
        if (i == j) continue;  // diagonal term is exactly 0
        float dd = 0.f;
#pragma unroll
        for (int c = 0; c < C; c++) {
          const float t = m[i][c] - m[j][c];
          dd += t * t;
        }
        const float r = fmaxf(DD - sqrtf(dd), 0.f);
        p += r * r;
      }
    }
    v = (v + s) / (float)K;
    d = (d + p) / (float)(2 * K * (K - 1));
  }
  out[0] = v / (float)B;
  out[1] = d / (float)B;
}

}  // namespace

extern "C" void kernel_launch(void* const* d_in, const int* in_sizes, int n_in,
                              void* d_out, int out_size, void* d_ws,
                              size_t ws_size, hipStream_t stream) {
  const float* emb = (const float*)d_in[0];
  const int* lab = (const int*)d_in[1];
  float* out = (float*)d_out;
  float* ws = (float*)d_ws;

  dim3 grid(GX, B);
  pass1_kernel<<<grid, NT, 0, stream>>>(emb, lab, ws);
  pass2_kernel<<<grid, NT, 0, stream>>>(emb, lab, ws);
  finalize_kernel<<<1, NT, 0, stream>>>(ws, out);
}